// Round 3
// baseline (4761.371 us; speedup 1.0000x reference)
//
#include <hip/hip_runtime.h>

#define NN   768
#define H    100
#define HP   128
#define TR   32
#define ITERS 3

__device__ __forceinline__ void fma4(float4& a, float s, const float4& b) {
  a.x = fmaf(s, b.x, a.x);
  a.y = fmaf(s, b.y, a.y);
  a.z = fmaf(s, b.z, a.z);
  a.w = fmaf(s, b.w, a.w);
}

// ---------------------------------------------------------------------------
// h = node_feats @ W_node + b_node      (768x32 @ 32x100)
__global__ void k_init_h(const float* __restrict__ nf, const float* __restrict__ Wn,
                         const float* __restrict__ bn, float* __restrict__ h) {
  const int gid = blockIdx.x * 256 + threadIdx.x;   // grid sized exactly NN*H/256
  const int i = gid / H;
  const int k = gid - i * H;
  float acc = bn[k];
#pragma unroll
  for (int m = 0; m < 32; ++m) acc = fmaf(nf[i * 32 + m], Wn[m * H + k], acc);
  h[gid] = acc;
}

// ---------------------------------------------------------------------------
// e = edge_attr @ W_edge + b_edge       (N^2 x16 @ 16x100), 8 rows per block
__global__ void k_init_e(const float* __restrict__ ea, const float* __restrict__ We,
                         const float* __restrict__ be, float* __restrict__ e) {
  __shared__ float Wsh[16][HP];
  __shared__ float bsh[HP];
  const int tid = threadIdx.x;
  for (int idx = tid; idx < 16 * HP; idx += 256) {
    const int m = idx >> 7, k = idx & (HP - 1);
    Wsh[m][k] = (k < H) ? We[m * H + k] : 0.f;
  }
  if (tid < HP) bsh[tid] = (tid < H) ? be[tid] : 0.f;
  __syncthreads();

  const int r  = tid >> 5;
  const int c0 = (tid & 31) * 4;
  const int row = blockIdx.x * 8 + r;
  const float* ear = ea + row * 16;
  const float4 a0 = *(const float4*)(ear + 0);
  const float4 a1 = *(const float4*)(ear + 4);
  const float4 a2 = *(const float4*)(ear + 8);
  const float4 a3 = *(const float4*)(ear + 12);
  float4 acc = *(const float4*)&bsh[c0];
#define STEP(m, s) { const float4 wv = *(const float4*)&Wsh[m][c0]; fma4(acc, s, wv); }
  STEP(0, a0.x) STEP(1, a0.y) STEP(2, a0.z) STEP(3, a0.w)
  STEP(4, a1.x) STEP(5, a1.y) STEP(6, a1.z) STEP(7, a1.w)
  STEP(8, a2.x) STEP(9, a2.y) STEP(10, a2.z) STEP(11, a2.w)
  STEP(12, a3.x) STEP(13, a3.y) STEP(14, a3.z) STEP(15, a3.w)
#undef STEP
  if (c0 < H) *(float4*)&e[row * H + c0] = acc;
}

// ---------------------------------------------------------------------------
// f_i = h @ W_i, f_j = h @ W_j  (no bias), written padded to HP cols (zeros)
__global__ void k_fifj(const float* __restrict__ h, const float* __restrict__ Wi,
                       const float* __restrict__ Wj, float* __restrict__ fi,
                       float* __restrict__ fj) {
  __shared__ float hsh[104];
  const int i = blockIdx.x;
  const int tid = threadIdx.x;
  const int which = tid >> 7;
  const int k = tid & (HP - 1);
  if (tid < H) hsh[tid] = h[i * H + tid];
  __syncthreads();
  const float* W = which ? Wj : Wi;
  float* f = which ? fj : fi;
  float acc = 0.f;
  if (k < H) {
    for (int m = 0; m < H; ++m) acc = fmaf(hsh[m], W[m * H + k], acc);
  }
  f[i * HP + k] = acc;   // k>=H -> 0 padding
}

// ---------------------------------------------------------------------------
// dots[i*N+j] = dot(f_i[i,:], f_j[j,:])   (16x16 output tile per block)
__global__ void k_dots(const float* __restrict__ fi, const float* __restrict__ fj,
                       float* __restrict__ dv) {
  __shared__ float fish[16][132];
  __shared__ float fjsh[16][132];
  const int tx = threadIdx.x, ty = threadIdx.y;
  const int i0 = blockIdx.y * 16, j0 = blockIdx.x * 16;
  const int tid = ty * 16 + tx;
  for (int idx = tid; idx < 16 * HP; idx += 256) {
    const int r = idx >> 7, c = idx & (HP - 1);
    fish[r][c] = fi[(i0 + r) * HP + c];
    fjsh[r][c] = fj[(j0 + r) * HP + c];
  }
  __syncthreads();
  float acc = 0.f;
#pragma unroll
  for (int kk = 0; kk < HP; kk += 4) {
    const float4 a = *(const float4*)&fish[ty][kk];
    const float4 b = *(const float4*)&fjsh[tx][kk];
    acc += a.x * b.x + a.y * b.y + a.z * b.z + a.w * b.w;
  }
  dv[(i0 + ty) * NN + (j0 + tx)] = acc;
}

// ---------------------------------------------------------------------------
// Fused edge update for TR=32 rows (all same i):
//   f   = relu(e @ W_eij + b_eij + dots)
//   e  += f @ W_de + b_de            (in place)
//   S[i] += sum_rows(e_new)          (for the linear dV trick)
#define MATVEC_PHASE(Wsh, SRC)                                                     \
  for (int mm = 0; mm < H; mm += 4) {                                              \
    const float4 w0v = *(const float4*)&Wsh[mm + 0][c0];                           \
    const float4 w1v = *(const float4*)&Wsh[mm + 1][c0];                           \
    const float4 w2v = *(const float4*)&Wsh[mm + 2][c0];                           \
    const float4 w3v = *(const float4*)&Wsh[mm + 3][c0];                           \
    float4 ev;                                                                     \
    ev = *(const float4*)&SRC[r0][mm];                                             \
    fma4(acc0, ev.x, w0v); fma4(acc0, ev.y, w1v); fma4(acc0, ev.z, w2v); fma4(acc0, ev.w, w3v); \
    ev = *(const float4*)&SRC[r1][mm];                                             \
    fma4(acc1, ev.x, w0v); fma4(acc1, ev.y, w1v); fma4(acc1, ev.z, w2v); fma4(acc1, ev.w, w3v); \
    ev = *(const float4*)&SRC[r2][mm];                                             \
    fma4(acc2, ev.x, w0v); fma4(acc2, ev.y, w1v); fma4(acc2, ev.z, w2v); fma4(acc2, ev.w, w3v); \
    ev = *(const float4*)&SRC[r3][mm];                                             \
    fma4(acc3, ev.x, w0v); fma4(acc3, ev.y, w1v); fma4(acc3, ev.z, w2v); fma4(acc3, ev.w, w3v); \
  }

__global__ __launch_bounds__(256, 1) void k_edge(
    const float* __restrict__ Weij, const float* __restrict__ beij,
    const float* __restrict__ Wde,  const float* __restrict__ bde,
    const float* __restrict__ dv,   float* __restrict__ e, float* __restrict__ S) {
  __shared__ float W1[H][HP];      // 51.2 KB
  __shared__ float W2[H][HP];      // 51.2 KB
  __shared__ float esh[TR][132];   // 16.9 KB
  __shared__ float fsh[TR][132];   // 16.9 KB
  __shared__ float b1[HP], b2[HP], sacc[HP];
  __shared__ float dsh[TR];

  const int tid = threadIdx.x;
  const int row0 = blockIdx.x * TR;      // TR divides NN -> whole block same i
  const int i = row0 / NN;

  for (int idx = tid; idx < H * HP; idx += 256) {
    const int m = idx >> 7, k = idx & (HP - 1);
    float w1 = 0.f, w2 = 0.f;
    if (k < H) { w1 = Weij[m * H + k]; w2 = Wde[m * H + k]; }
    W1[m][k] = w1; W2[m][k] = w2;
  }
  if (tid < HP) {
    b1[tid] = (tid < H) ? beij[tid] : 0.f;
    b2[tid] = (tid < H) ? bde[tid]  : 0.f;
    sacc[tid] = 0.f;
  }
  if (tid < TR) dsh[tid] = dv[row0 + tid];
  for (int idx = tid; idx < TR * H; idx += 256) {
    const int r = idx / H, m = idx - r * H;
    esh[r][m] = e[(row0 + r) * H + m];
  }
  __syncthreads();

  const int tc = tid & 31;
  const int tr = tid >> 5;
  const int c0 = tc * 4;
  const int r0 = tr, r1 = tr + 8, r2 = tr + 16, r3 = tr + 24;

  float4 acc0, acc1, acc2, acc3;
  { const float4 b = *(const float4*)&b1[c0]; acc0 = b; acc1 = b; acc2 = b; acc3 = b; }
  MATVEC_PHASE(W1, esh)
  {
    float d; float4 v;
    d = dsh[r0]; v = acc0;
    v.x = fmaxf(v.x + d, 0.f); v.y = fmaxf(v.y + d, 0.f);
    v.z = fmaxf(v.z + d, 0.f); v.w = fmaxf(v.w + d, 0.f);
    *(float4*)&fsh[r0][c0] = v;
    d = dsh[r1]; v = acc1;
    v.x = fmaxf(v.x + d, 0.f); v.y = fmaxf(v.y + d, 0.f);
    v.z = fmaxf(v.z + d, 0.f); v.w = fmaxf(v.w + d, 0.f);
    *(float4*)&fsh[r1][c0] = v;
    d = dsh[r2]; v = acc2;
    v.x = fmaxf(v.x + d, 0.f); v.y = fmaxf(v.y + d, 0.f);
    v.z = fmaxf(v.z + d, 0.f); v.w = fmaxf(v.w + d, 0.f);
    *(float4*)&fsh[r2][c0] = v;
    d = dsh[r3]; v = acc3;
    v.x = fmaxf(v.x + d, 0.f); v.y = fmaxf(v.y + d, 0.f);
    v.z = fmaxf(v.z + d, 0.f); v.w = fmaxf(v.w + d, 0.f);
    *(float4*)&fsh[r3][c0] = v;
  }
  __syncthreads();

  { const float4 b = *(const float4*)&b2[c0]; acc0 = b; acc1 = b; acc2 = b; acc3 = b; }
  MATVEC_PHASE(W2, fsh)

  float4 esum = make_float4(0.f, 0.f, 0.f, 0.f);
  {
    float4 eo, en;
    eo = *(const float4*)&esh[r0][c0];
    en.x = eo.x + acc0.x; en.y = eo.y + acc0.y; en.z = eo.z + acc0.z; en.w = eo.w + acc0.w;
    if (c0 < H) *(float4*)&e[(row0 + r0) * H + c0] = en;
    esum.x += en.x; esum.y += en.y; esum.z += en.z; esum.w += en.w;
    eo = *(const float4*)&esh[r1][c0];
    en.x = eo.x + acc1.x; en.y = eo.y + acc1.y; en.z = eo.z + acc1.z; en.w = eo.w + acc1.w;
    if (c0 < H) *(float4*)&e[(row0 + r1) * H + c0] = en;
    esum.x += en.x; esum.y += en.y; esum.z += en.z; esum.w += en.w;
    eo = *(const float4*)&esh[r2][c0];
    en.x = eo.x + acc2.x; en.y = eo.y + acc2.y; en.z = eo.z + acc2.z; en.w = eo.w + acc2.w;
    if (c0 < H) *(float4*)&e[(row0 + r2) * H + c0] = en;
    esum.x += en.x; esum.y += en.y; esum.z += en.z; esum.w += en.w;
    eo = *(const float4*)&esh[r3][c0];
    en.x = eo.x + acc3.x; en.y = eo.y + acc3.y; en.z = eo.z + acc3.z; en.w = eo.w + acc3.w;
    if (c0 < H) *(float4*)&e[(row0 + r3) * H + c0] = en;
    esum.x += en.x; esum.y += en.y; esum.z += en.z; esum.w += en.w;
  }
  if (c0 < H) {
    atomicAdd(&sacc[c0 + 0], esum.x);
    atomicAdd(&sacc[c0 + 1], esum.y);
    atomicAdd(&sacc[c0 + 2], esum.z);
    atomicAdd(&sacc[c0 + 3], esum.w);
  }
  __syncthreads();
  if (tid < H) atomicAdd(&S[i * H + tid], sacc[tid]);
}

// ---------------------------------------------------------------------------
// dV = S @ W_dv1 + N*b_dv1 ;  h += dV @ W_dv2 + b_dv2
__global__ void k_node(const float* __restrict__ S, const float* __restrict__ Wdv1,
                       const float* __restrict__ bdv1, const float* __restrict__ Wdv2,
                       const float* __restrict__ bdv2, float* __restrict__ h) {
  __shared__ float Ssh[104];
  __shared__ float t1[104];
  const int i = blockIdx.x;
  const int k = threadIdx.x;
  if (k < H) Ssh[k] = S[i * H + k];
  __syncthreads();
  if (k < H) {
    float acc = 768.0f * bdv1[k];
    for (int m = 0; m < H; ++m) acc = fmaf(Ssh[m], Wdv1[m * H + k], acc);
    t1[k] = acc;
  }
  __syncthreads();
  if (k < H) {
    float acc = bdv2[k];
    for (int m = 0; m < H; ++m) acc = fmaf(t1[m], Wdv2[m * H + k], acc);
    h[i * H + k] += acc;
  }
}

// ---------------------------------------------------------------------------
extern "C" void kernel_launch(void* const* d_in, const int* in_sizes, int n_in,
                              void* d_out, int out_size, void* d_ws, size_t ws_size,
                              hipStream_t stream) {
  const float* nf   = (const float*)d_in[0];
  const float* ea   = (const float*)d_in[1];
  const float* Wn   = (const float*)d_in[2];
  const float* bn   = (const float*)d_in[3];
  const float* We   = (const float*)d_in[4];
  const float* be   = (const float*)d_in[5];
  const float* Weij = (const float*)d_in[6];
  const float* beij = (const float*)d_in[7];
  const float* Wi   = (const float*)d_in[8];
  const float* Wj   = (const float*)d_in[9];
  const float* Wde  = (const float*)d_in[10];
  const float* bde  = (const float*)d_in[11];
  const float* Wdv1 = (const float*)d_in[12];
  const float* bdv1 = (const float*)d_in[13];
  const float* Wdv2 = (const float*)d_in[14];
  const float* bdv2 = (const float*)d_in[15];

  float* h = (float*)d_out;            // (768,100) output 0
  float* e = h + NN * H;               // (768*768,100) output 1 (in-place)

  float* ws = (float*)d_ws;            // scratch: 3.45 MB total
  float* fi = ws;                      // NN*HP
  float* fj = fi + NN * HP;            // NN*HP
  float* dv = fj + NN * HP;            // NN*NN
  float* S  = dv + NN * NN;            // NN*H

  k_init_h<<<(NN * H) / 256, 256, 0, stream>>>(nf, Wn, bn, h);
  k_init_e<<<(NN * NN) / 8, 256, 0, stream>>>(ea, We, be, e);
  for (int it = 0; it < ITERS; ++it) {
    k_fifj<<<NN, 256, 0, stream>>>(h, Wi, Wj, fi, fj);
    k_dots<<<dim3(NN / 16, NN / 16), dim3(16, 16), 0, stream>>>(fi, fj, dv);
    hipMemsetAsync(S, 0, NN * H * sizeof(float), stream);
    k_edge<<<(NN * NN) / TR, 256, 0, stream>>>(Weij, beij, Wde, bde, dv, e, S);
    k_node<<<NN, 128, 0, stream>>>(S, Wdv1, bdv1, Wdv2, bdv2, h);
  }
}

// Round 5
// 1746.617 us; speedup vs baseline: 2.7261x; 2.7261x over previous
//
#include <hip/hip_runtime.h>

#define NN   768
#define H    100
#define ITERS 3
#define BM   32          // e-rows per block in k_edge_mfma
#define LDP  136         // LDS stride (bf16 elems) for split planes: 272B -> 2-way-free
#define LDE  104         // LDS stride (f32 elems) for e fp32 copy

typedef __attribute__((ext_vector_type(8))) short bf16x8;
typedef __attribute__((ext_vector_type(4))) float f32x4;

__device__ __forceinline__ unsigned short bf16_rne(float f) {
  union { float f; unsigned u; } x; x.f = f;
  unsigned r = x.u + 0x7FFF + ((x.u >> 16) & 1);
  return (unsigned short)(r >> 16);
}
__device__ __forceinline__ float bf16_to_f(unsigned short u) {
  union { unsigned u; float f; } x; x.u = ((unsigned)u) << 16;
  return x.f;
}

__device__ __forceinline__ void fma4(float4& a, float s, const float4& b) {
  a.x = fmaf(s, b.x, a.x);
  a.y = fmaf(s, b.y, a.y);
  a.z = fmaf(s, b.z, a.z);
  a.w = fmaf(s, b.w, a.w);
}

// ---------------------------------------------------------------------------
// h = node_feats @ W_node + b_node      (768x32 @ 32x100)
__global__ void k_init_h(const float* __restrict__ nf, const float* __restrict__ Wn,
                         const float* __restrict__ bn, float* __restrict__ h) {
  const int gid = blockIdx.x * 256 + threadIdx.x;
  const int i = gid / H;
  const int k = gid - i * H;
  float acc = bn[k];
#pragma unroll
  for (int m = 0; m < 32; ++m) acc = fmaf(nf[i * 32 + m], Wn[m * H + k], acc);
  h[gid] = acc;
}

// ---------------------------------------------------------------------------
// e = edge_attr @ W_edge + b_edge       (N^2 x16 @ 16x100), 8 rows per block
__global__ void k_init_e(const float* __restrict__ ea, const float* __restrict__ We,
                         const float* __restrict__ be, float* __restrict__ e) {
  __shared__ float Wsh[16][128];
  __shared__ float bsh[128];
  const int tid = threadIdx.x;
  for (int idx = tid; idx < 16 * 128; idx += 256) {
    const int m = idx >> 7, k = idx & 127;
    Wsh[m][k] = (k < H) ? We[m * H + k] : 0.f;
  }
  if (tid < 128) bsh[tid] = (tid < H) ? be[tid] : 0.f;
  __syncthreads();

  const int r  = tid >> 5;
  const int c0 = (tid & 31) * 4;
  const int row = blockIdx.x * 8 + r;
  const float* ear = ea + row * 16;
  const float4 a0 = *(const float4*)(ear + 0);
  const float4 a1 = *(const float4*)(ear + 4);
  const float4 a2 = *(const float4*)(ear + 8);
  const float4 a3 = *(const float4*)(ear + 12);
  float4 acc = *(const float4*)&bsh[c0];
#define STEP(m, s) { const float4 wv = *(const float4*)&Wsh[m][c0]; fma4(acc, s, wv); }
  STEP(0, a0.x) STEP(1, a0.y) STEP(2, a0.z) STEP(3, a0.w)
  STEP(4, a1.x) STEP(5, a1.y) STEP(6, a1.z) STEP(7, a1.w)
  STEP(8, a2.x) STEP(9, a2.y) STEP(10, a2.z) STEP(11, a2.w)
  STEP(12, a3.x) STEP(13, a3.y) STEP(14, a3.z) STEP(15, a3.w)
#undef STEP
  if (c0 < H) *(float4*)&e[row * H + c0] = acc;
}

// ---------------------------------------------------------------------------
// f_i = h @ W_i, f_j = h @ W_j  (no bias), written padded to 128 cols (zeros)
__global__ void k_fifj(const float* __restrict__ h, const float* __restrict__ Wi,
                       const float* __restrict__ Wj, float* __restrict__ fi,
                       float* __restrict__ fj) {
  __shared__ float hsh[104];
  const int i = blockIdx.x;
  const int tid = threadIdx.x;
  const int which = tid >> 7;
  const int k = tid & 127;
  if (tid < H) hsh[tid] = h[i * H + tid];
  __syncthreads();
  const float* W = which ? Wj : Wi;
  float* f = which ? fj : fi;
  float acc = 0.f;
  if (k < H) {
    for (int m = 0; m < H; ++m) acc = fmaf(hsh[m], W[m * H + k], acc);
  }
  f[i * 128 + k] = acc;
}

// ---------------------------------------------------------------------------
// dots[i*N+j] = dot(f_i[i,:], f_j[j,:])
__global__ void k_dots(const float* __restrict__ fi, const float* __restrict__ fj,
                       float* __restrict__ dv) {
  __shared__ float fish[16][132];
  __shared__ float fjsh[16][132];
  const int tx = threadIdx.x, ty = threadIdx.y;
  const int i0 = blockIdx.y * 16, j0 = blockIdx.x * 16;
  const int tid = ty * 16 + tx;
  for (int idx = tid; idx < 16 * 128; idx += 256) {
    const int r = idx >> 7, c = idx & 127;
    fish[r][c] = fi[(i0 + r) * 128 + c];
    fjsh[r][c] = fj[(j0 + r) * 128 + c];
  }
  __syncthreads();
  float acc = 0.f;
#pragma unroll
  for (int kk = 0; kk < 128; kk += 4) {
    const float4 a = *(const float4*)&fish[ty][kk];
    const float4 b = *(const float4*)&fjsh[tx][kk];
    acc += a.x * b.x + a.y * b.y + a.z * b.z + a.w * b.w;
  }
  dv[(i0 + ty) * NN + (j0 + tx)] = acc;
}

// ---------------------------------------------------------------------------
// Pre-split W_eij (wsel 0) and W_de (wsel 1) into 3 bf16 planes, K-major,
// padded to [112 cols][128 k]. Layout: Wsp[((wsel*3+plane)*112 + col)*128 + k]
__global__ void k_splitW(const float* __restrict__ W1, const float* __restrict__ W2,
                         unsigned short* __restrict__ Wsp) {
  const int b = blockIdx.x;            // 2*112 blocks
  const int wsel = b / 112;
  const int col = b % 112;
  const int k = threadIdx.x;           // 128
  const float* Wsrc = wsel ? W2 : W1;
  const float v = (col < H && k < H) ? Wsrc[k * H + col] : 0.f;
  const unsigned short hi = bf16_rne(v);
  const float r1 = v - bf16_to_f(hi);
  const unsigned short mi = bf16_rne(r1);
  const unsigned short lo = bf16_rne(r1 - bf16_to_f(mi));
  unsigned short* Wd = Wsp + (size_t)(wsel * 3) * 112 * 128;
  Wd[(0 * 112 + col) * 128 + k] = hi;
  Wd[(1 * 112 + col) * 128 + k] = mi;
  Wd[(2 * 112 + col) * 128 + k] = lo;
}

// ---------------------------------------------------------------------------
// Load one phase's weight fragments into registers.
// wf[slot][kstep][plane]; B-frag: lane holds B[k0..k0+7][col], col = ct*16+l15.
__device__ __forceinline__ void loadw(bf16x8 (&wf)[2][4][3],
                                      const unsigned short* __restrict__ Wsp,
                                      int wsel, int ct0, int ct1, bool has1,
                                      int l15, int lq) {
#pragma unroll
  for (int s = 0; s < 2; ++s) {
    if (s && !has1) continue;
    const int ct = s ? ct1 : ct0;
    const unsigned short* base = Wsp + ((size_t)(wsel * 3) * 112 + ct * 16 + l15) * 128;
#pragma unroll
    for (int pl = 0; pl < 3; ++pl)
#pragma unroll
      for (int ks = 0; ks < 4; ++ks)
        wf[s][ks][pl] = *(const bf16x8*)(base + (size_t)pl * 112 * 128 + ks * 32 + 8 * lq);
  }
}

// ---------------------------------------------------------------------------
// Fused edge update (MFMA, bf16x6 fp32-emulation).
//   phase1: F = relu(E @ W1 + b1 + dots)  -> split -> P planes (recycled)
//   phase2: E += F @ W2 + b2 ; S[i] += rowsum(E_new)
__global__ __launch_bounds__(256, 2) void k_edge_mfma(
    const unsigned short* __restrict__ Wsp,
    const float* __restrict__ beij, const float* __restrict__ bde,
    const float* __restrict__ dv, float* __restrict__ e, float* __restrict__ S) {
  __shared__ __align__(16) unsigned short P[3][BM][LDP];  // 26.1 KB, E then F splits
  __shared__ __align__(16) float esh[BM][LDE];            // 13.3 KB fp32 copy of E
  __shared__ float b1sh[112], b2sh[112], sacc[112];
  __shared__ float dsh[BM];

  const int tid = threadIdx.x;
  const int lane = tid & 63;
  const int w = tid >> 6;
  const int l15 = lane & 15;
  const int lq  = lane >> 4;
  const int row0 = blockIdx.x * BM;
  const int i = blockIdx.x / (NN / BM);

  if (tid < 112) {
    b1sh[tid] = (tid < H) ? beij[tid] : 0.f;
    b2sh[tid] = (tid < H) ? bde[tid]  : 0.f;
    sacc[tid] = 0.f;
  }
  if (tid < BM) dsh[tid] = dv[row0 + tid];
  // zero K-pad region k in [100,128) of all planes
  for (int idx = tid; idx < 3 * BM * 28; idx += 256) {
    const int pl = idx / (BM * 28), rem = idx % (BM * 28);
    P[pl][rem / 28][100 + rem % 28] = 0;
  }
  // stage E: fp32 copy + 3-way bf16 split into P planes
  for (int idx = tid; idx < BM * 25; idx += 256) {
    const int r = idx / 25, c4 = (idx % 25) * 4;
    const float4 v = *(const float4*)&e[(row0 + r) * H + c4];
    *(float4*)&esh[r][c4] = v;
    const float vv[4] = {v.x, v.y, v.z, v.w};
    ushort4 hs, ms, ls;
    unsigned short* hp = (unsigned short*)&hs;
    unsigned short* mp = (unsigned short*)&ms;
    unsigned short* lp = (unsigned short*)&ls;
#pragma unroll
    for (int q = 0; q < 4; ++q) {
      const unsigned short hi = bf16_rne(vv[q]);
      const float r1 = vv[q] - bf16_to_f(hi);
      const unsigned short mi = bf16_rne(r1);
      const unsigned short lo = bf16_rne(r1 - bf16_to_f(mi));
      hp[q] = hi; mp[q] = mi; lp[q] = lo;
    }
    *(ushort4*)&P[0][r][c4] = hs;
    *(ushort4*)&P[1][r][c4] = ms;
    *(ushort4*)&P[2][r][c4] = ls;
  }

  const int ct0 = 2 * w, ct1 = 2 * w + 1;
  const bool has1 = (ct1 <= 6);      // col tile 7 is all-padding -> skipped

  bf16x8 wf[2][4][3];
  loadw(wf, Wsp, 0, ct0, ct1, has1, l15, lq);
  __syncthreads();

  f32x4 acc[2][2];
#define GEMM_PHASE() do {                                                      \
    _Pragma("unroll") for (int s = 0; s < 2; ++s)                              \
      _Pragma("unroll") for (int rt = 0; rt < 2; ++rt)                         \
        acc[s][rt] = (f32x4){0.f, 0.f, 0.f, 0.f};                              \
    _Pragma("unroll") for (int ks = 0; ks < 4; ++ks) {                         \
      bf16x8 af[2][3];                                                         \
      _Pragma("unroll") for (int rt = 0; rt < 2; ++rt)                         \
        _Pragma("unroll") for (int pl = 0; pl < 3; ++pl)                       \
          af[rt][pl] = *(const bf16x8*)&P[pl][rt * 16 + l15][ks * 32 + 8 * lq];\
      _Pragma("unroll") for (int s = 0; s < 2; ++s) {                          \
        if (s && !has1) continue;                                              \
        _Pragma("unroll") for (int rt = 0; rt < 2; ++rt) {                     \
          f32x4 c = acc[s][rt];                                                \
          c = __builtin_amdgcn_mfma_f32_16x16x32_bf16(af[rt][0], wf[s][ks][0], c, 0, 0, 0); \
          c = __builtin_amdgcn_mfma_f32_16x16x32_bf16(af[rt][1], wf[s][ks][0], c, 0, 0, 0); \
          c = __builtin_amdgcn_mfma_f32_16x16x32_bf16(af[rt][0], wf[s][ks][1], c, 0, 0, 0); \
          c = __builtin_amdgcn_mfma_f32_16x16x32_bf16(af[rt][2], wf[s][ks][0], c, 0, 0, 0); \
          c = __builtin_amdgcn_mfma_f32_16x16x32_bf16(af[rt][0], wf[s][ks][2], c, 0, 0, 0); \
          c = __builtin_amdgcn_mfma_f32_16x16x32_bf16(af[rt][1], wf[s][ks][1], c, 0, 0, 0); \
          acc[s][rt] = c;                                                      \
        }                                                                      \
      }                                                                        \
    }                                                                          \
  } while (0)

  GEMM_PHASE();          // phase 1: E @ W1
  __syncthreads();       // all E-plane reads complete before F overwrites

  loadw(wf, Wsp, 1, ct0, ct1, has1, l15, lq);   // W2 frags (overlaps epilogue)

  // epilogue 1: relu(C + dots + b1) -> split -> F planes (recycle P)
#pragma unroll
  for (int s = 0; s < 2; ++s) {
    if (s && !has1) continue;
    const int col = (s ? ct1 : ct0) * 16 + l15;
    const float bias = b1sh[col];
#pragma unroll
    for (int rt = 0; rt < 2; ++rt) {
#pragma unroll
      for (int r = 0; r < 4; ++r) {
        const int row = rt * 16 + lq * 4 + r;
        float v = acc[s][rt][r] + dsh[row] + bias;
        v = fmaxf(v, 0.f);
        const unsigned short hi = bf16_rne(v);
        const float r1 = v - bf16_to_f(hi);
        const unsigned short mi = bf16_rne(r1);
        const unsigned short lo = bf16_rne(r1 - bf16_to_f(mi));
        P[0][row][col] = hi;
        P[1][row][col] = mi;
        P[2][row][col] = lo;
      }
    }
  }
  __syncthreads();       // F planes visible to all waves

  GEMM_PHASE();          // phase 2: F @ W2

  // epilogue 2: E += C + b2 ; store + rowsum
#pragma unroll
  for (int s = 0; s < 2; ++s) {
    if (s && !has1) continue;
    const int col = (s ? ct1 : ct0) * 16 + l15;
    const float bias = b2sh[col];
    float psum = 0.f;
#pragma unroll
    for (int rt = 0; rt < 2; ++rt) {
#pragma unroll
      for (int r = 0; r < 4; ++r) {
        const int row = rt * 16 + lq * 4 + r;
        const float en = esh[row][col < LDE ? col : 0] + acc[s][rt][r] + bias;
        if (col < H) {
          e[(size_t)(row0 + row) * H + col] = en;
          psum += en;
        }
      }
    }
    if (col < H) atomicAdd(&sacc[col], psum);
  }
  __syncthreads();
  if (tid < H) atomicAdd(&S[i * H + tid], sacc[tid]);
}

// ---------------------------------------------------------------------------
// dV = S @ W_dv1 + N*b_dv1 ;  h += dV @ W_dv2 + b_dv2
__global__ void k_node(const float* __restrict__ S, const float* __restrict__ Wdv1,
                       const float* __restrict__ bdv1, const float* __restrict__ Wdv2,
                       const float* __restrict__ bdv2, float* __restrict__ h) {
  __shared__ float Ssh[104];
  __shared__ float t1[104];
  const int i = blockIdx.x;
  const int k = threadIdx.x;
  if (k < H) Ssh[k] = S[i * H + k];
  __syncthreads();
  if (k < H) {
    float acc = 768.0f * bdv1[k];
    for (int m = 0; m < H; ++m) acc = fmaf(Ssh[m], Wdv1[m * H + k], acc);
    t1[k] = acc;
  }
  __syncthreads();
  if (k < H) {
    float acc = bdv2[k];
    for (int m = 0; m < H; ++m) acc = fmaf(t1[m], Wdv2[m * H + k], acc);
    h[i * H + k] += acc;
  }
}

// ---------------------------------------------------------------------------
extern "C" void kernel_launch(void* const* d_in, const int* in_sizes, int n_in,
                              void* d_out, int out_size, void* d_ws, size_t ws_size,
                              hipStream_t stream) {
  const float* nf   = (const float*)d_in[0];
  const float* ea   = (const float*)d_in[1];
  const float* Wn   = (const float*)d_in[2];
  const float* bn   = (const float*)d_in[3];
  const float* We   = (const float*)d_in[4];
  const float* be   = (const float*)d_in[5];
  const float* Weij = (const float*)d_in[6];
  const float* beij = (const float*)d_in[7];
  const float* Wi   = (const float*)d_in[8];
  const float* Wj   = (const float*)d_in[9];
  const float* Wde  = (const float*)d_in[10];
  const float* bde  = (const float*)d_in[11];
  const float* Wdv1 = (const float*)d_in[12];
  const float* bdv1 = (const float*)d_in[13];
  const float* Wdv2 = (const float*)d_in[14];
  const float* bdv2 = (const float*)d_in[15];

  float* h = (float*)d_out;            // (768,100) output 0
  float* e = h + NN * H;               // (768*768,100) output 1 (in-place)

  float* ws = (float*)d_ws;
  float* fi = ws;                      // NN*128 f32  (also reused for Wsp)
  float* fj = fi + NN * 128;           // NN*128 f32
  float* dv = fj + NN * 128;           // NN*NN f32
  float* S  = dv + NN * NN;            // NN*H  f32
  // W split planes overlap the fi region: fi is dead after k_dots each iter,
  // rebuilt by k_fifj next iter. 2*3*112*128 bf16 = 172 KB < fi's 393 KB.
  unsigned short* Wsp = (unsigned short*)fi;

  k_init_h<<<(NN * H) / 256, 256, 0, stream>>>(nf, Wn, bn, h);
  k_init_e<<<(NN * NN) / 8, 256, 0, stream>>>(ea, We, be, e);
  for (int it = 0; it < ITERS; ++it) {
    k_fifj<<<NN, 256, 0, stream>>>(h, Wi, Wj, fi, fj);
    k_dots<<<dim3(NN / 16, NN / 16), dim3(16, 16), 0, stream>>>(fi, fj, dv);
    hipMemsetAsync(S, 0, NN * H * sizeof(float), stream);
    k_splitW<<<2 * 112, 128, 0, stream>>>(Weij, Wde, Wsp);
    k_edge_mfma<<<(NN * NN) / BM, 256, 0, stream>>>(Wsp, beij, bde, dv, e, S);
    k_node<<<NN, 128, 0, stream>>>(S, Wdv1, bdv1, Wdv2, bdv2, h);
  }
}

// Round 6
// 1178.748 us; speedup vs baseline: 4.0393x; 1.4818x over previous
//
#include <hip/hip_runtime.h>

#define NN   768
#define H    100
#define ITERS 3
#define BM   32          // e-rows per block in k_edge_mfma
#define LDP  136         // LDS stride (bf16 elems) for split planes: 272B -> 2-way-free

typedef __attribute__((ext_vector_type(8))) short bf16x8;
typedef __attribute__((ext_vector_type(4))) float f32x4;

__device__ __forceinline__ unsigned short bf16_rne(float f) {
  union { float f; unsigned u; } x; x.f = f;
  unsigned r = x.u + 0x7FFF + ((x.u >> 16) & 1);
  return (unsigned short)(r >> 16);
}
__device__ __forceinline__ float bf16_to_f(unsigned short u) {
  union { unsigned u; float f; } x; x.u = ((unsigned)u) << 16;
  return x.f;
}

__device__ __forceinline__ void fma4(float4& a, float s, const float4& b) {
  a.x = fmaf(s, b.x, a.x);
  a.y = fmaf(s, b.y, a.y);
  a.z = fmaf(s, b.z, a.z);
  a.w = fmaf(s, b.w, a.w);
}

// ---------------------------------------------------------------------------
// h = node_feats @ W_node + b_node      (768x32 @ 32x100)
__global__ void k_init_h(const float* __restrict__ nf, const float* __restrict__ Wn,
                         const float* __restrict__ bn, float* __restrict__ h) {
  const int gid = blockIdx.x * 256 + threadIdx.x;
  const int i = gid / H;
  const int k = gid - i * H;
  float acc = bn[k];
#pragma unroll
  for (int m = 0; m < 32; ++m) acc = fmaf(nf[i * 32 + m], Wn[m * H + k], acc);
  h[gid] = acc;
}

// ---------------------------------------------------------------------------
// e = edge_attr @ W_edge + b_edge       (N^2 x16 @ 16x100), 8 rows per block
__global__ void k_init_e(const float* __restrict__ ea, const float* __restrict__ We,
                         const float* __restrict__ be, float* __restrict__ e) {
  __shared__ float Wsh[16][128];
  __shared__ float bsh[128];
  const int tid = threadIdx.x;
  for (int idx = tid; idx < 16 * 128; idx += 256) {
    const int m = idx >> 7, k = idx & 127;
    Wsh[m][k] = (k < H) ? We[m * H + k] : 0.f;
  }
  if (tid < 128) bsh[tid] = (tid < H) ? be[tid] : 0.f;
  __syncthreads();

  const int r  = tid >> 5;
  const int c0 = (tid & 31) * 4;
  const int row = blockIdx.x * 8 + r;
  const float* ear = ea + row * 16;
  const float4 a0 = *(const float4*)(ear + 0);
  const float4 a1 = *(const float4*)(ear + 4);
  const float4 a2 = *(const float4*)(ear + 8);
  const float4 a3 = *(const float4*)(ear + 12);
  float4 acc = *(const float4*)&bsh[c0];
#define STEP(m, s) { const float4 wv = *(const float4*)&Wsh[m][c0]; fma4(acc, s, wv); }
  STEP(0, a0.x) STEP(1, a0.y) STEP(2, a0.z) STEP(3, a0.w)
  STEP(4, a1.x) STEP(5, a1.y) STEP(6, a1.z) STEP(7, a1.w)
  STEP(8, a2.x) STEP(9, a2.y) STEP(10, a2.z) STEP(11, a2.w)
  STEP(12, a3.x) STEP(13, a3.y) STEP(14, a3.z) STEP(15, a3.w)
#undef STEP
  if (c0 < H) *(float4*)&e[row * H + c0] = acc;
}

// ---------------------------------------------------------------------------
// f_i = h @ W_i, f_j = h @ W_j  (no bias), written padded to 128 cols (zeros)
__global__ void k_fifj(const float* __restrict__ h, const float* __restrict__ Wi,
                       const float* __restrict__ Wj, float* __restrict__ fi,
                       float* __restrict__ fj) {
  __shared__ float hsh[104];
  const int i = blockIdx.x;
  const int tid = threadIdx.x;
  const int which = tid >> 7;
  const int k = tid & 127;
  if (tid < H) hsh[tid] = h[i * H + tid];
  __syncthreads();
  const float* W = which ? Wj : Wi;
  float* f = which ? fj : fi;
  float acc = 0.f;
  if (k < H) {
    for (int m = 0; m < H; ++m) acc = fmaf(hsh[m], W[m * H + k], acc);
  }
  f[i * 128 + k] = acc;
}

// ---------------------------------------------------------------------------
// dots[i*N+j] = dot(f_i[i,:], f_j[j,:])
__global__ void k_dots(const float* __restrict__ fi, const float* __restrict__ fj,
                       float* __restrict__ dv) {
  __shared__ float fish[16][132];
  __shared__ float fjsh[16][132];
  const int tx = threadIdx.x, ty = threadIdx.y;
  const int i0 = blockIdx.y * 16, j0 = blockIdx.x * 16;
  const int tid = ty * 16 + tx;
  for (int idx = tid; idx < 16 * 128; idx += 256) {
    const int r = idx >> 7, c = idx & 127;
    fish[r][c] = fi[(i0 + r) * 128 + c];
    fjsh[r][c] = fj[(j0 + r) * 128 + c];
  }
  __syncthreads();
  float acc = 0.f;
#pragma unroll
  for (int kk = 0; kk < 128; kk += 4) {
    const float4 a = *(const float4*)&fish[ty][kk];
    const float4 b = *(const float4*)&fjsh[tx][kk];
    acc += a.x * b.x + a.y * b.y + a.z * b.z + a.w * b.w;
  }
  dv[(i0 + ty) * NN + (j0 + tx)] = acc;
}

// ---------------------------------------------------------------------------
// Pre-split W_eij (wsel 0) and W_de (wsel 1) into 3 bf16 planes, pre-arranged
// as per-lane MFMA B-fragments:
//   Wf[frag][lane][8], frag = ((wsel*7 + ct)*4 + ks)*3 + pl
//   lane (l15,lq) holds B[k = ks*32+8*lq .. +7][col = ct*16+l15]
// One 16B read per (lane, frag) in the GEMM -> perfectly coalesced, L2-hot.
__global__ void k_splitW(const float* __restrict__ W1, const float* __restrict__ W2,
                         unsigned short* __restrict__ Wf) {
  const int b = blockIdx.x;            // b = (wsel*7 + ct)*4 + ks,  56 blocks
  const int wsel = b / 28;
  const int ct = (b % 28) / 4;
  const int ks = b % 4;
  const int lane = threadIdx.x;        // 64
  const int l15 = lane & 15, lq = lane >> 4;
  const int col = ct * 16 + l15;
  const float* Wsrc = wsel ? W2 : W1;
  unsigned short* out = Wf + (size_t)(b * 3) * 512 + lane * 8;  // 512 u16 per frag
#pragma unroll
  for (int q = 0; q < 8; ++q) {
    const int k = ks * 32 + 8 * lq + q;
    const float v = (col < H && k < H) ? Wsrc[k * H + col] : 0.f;
    const unsigned short hi = bf16_rne(v);
    const float r1 = v - bf16_to_f(hi);
    const unsigned short mi = bf16_rne(r1);
    const unsigned short lo = bf16_rne(r1 - bf16_to_f(mi));
    out[0 * 512 + q] = hi;
    out[1 * 512 + q] = mi;
    out[2 * 512 + q] = lo;
  }
}

// ---------------------------------------------------------------------------
// Fused edge update (MFMA, bf16x6 fp32-emulation).
//   phase1: F = relu(E @ W1 + b1 + dots)  -> split -> P planes (recycled)
//   phase2: E += F @ W2 + b2 ; S[i] += rowsum(E_new)
// LDS ~27.6 KB -> 5 blocks/CU; W frags loaded per-K-step from L2-hot Wf.
__global__ __launch_bounds__(256, 4) void k_edge_mfma(
    const unsigned short* __restrict__ Wf,
    const float* __restrict__ beij, const float* __restrict__ bde,
    const float* __restrict__ dv, float* __restrict__ e, float* __restrict__ S) {
  __shared__ __align__(16) unsigned short P[3][BM][LDP];  // 26.1 KB
  __shared__ float b1sh[112], b2sh[112], sacc[112];
  __shared__ float dsh[BM];

  const int tid = threadIdx.x;
  const int lane = tid & 63;
  const int w = tid >> 6;
  const int l15 = lane & 15;
  const int lq  = lane >> 4;
  const int row0 = blockIdx.x * BM;
  const int i = blockIdx.x / (NN / BM);

  if (tid < 112) {
    b1sh[tid] = (tid < H) ? beij[tid] : 0.f;
    b2sh[tid] = (tid < H) ? bde[tid]  : 0.f;
    sacc[tid] = 0.f;
  }
  if (tid < BM) dsh[tid] = dv[row0 + tid];
  // zero K-pad region k in [100,128) of all planes
  for (int idx = tid; idx < 3 * BM * 28; idx += 256) {
    const int pl = idx / (BM * 28), rem = idx % (BM * 28);
    P[pl][rem / 28][100 + rem % 28] = 0;
  }
  // stage E: 3-way bf16 split into P planes
  for (int idx = tid; idx < BM * 25; idx += 256) {
    const int r = idx / 25, c4 = (idx % 25) * 4;
    const float4 v = *(const float4*)&e[(size_t)(row0 + r) * H + c4];
    const float vv[4] = {v.x, v.y, v.z, v.w};
    ushort4 hs, ms, ls;
    unsigned short* hp = (unsigned short*)&hs;
    unsigned short* mp = (unsigned short*)&ms;
    unsigned short* lp = (unsigned short*)&ls;
#pragma unroll
    for (int q = 0; q < 4; ++q) {
      const unsigned short hi = bf16_rne(vv[q]);
      const float r1 = vv[q] - bf16_to_f(hi);
      const unsigned short mi = bf16_rne(r1);
      const unsigned short lo = bf16_rne(r1 - bf16_to_f(mi));
      hp[q] = hi; mp[q] = mi; lp[q] = lo;
    }
    *(ushort4*)&P[0][r][c4] = hs;
    *(ushort4*)&P[1][r][c4] = ms;
    *(ushort4*)&P[2][r][c4] = ls;
  }

  const int ct0 = 2 * w, ct1 = 2 * w + 1;
  const bool has1 = (ct1 <= 6);      // col tile 7 is all-padding -> skipped

  __syncthreads();

  f32x4 acc[2][2];
  // 6-product bf16 emulation: hh, mh, hm, lh, hl, mm  (residual ~2^-24)
#define GEMM_PHASE(WSEL) do {                                                  \
    _Pragma("unroll") for (int s = 0; s < 2; ++s)                              \
      _Pragma("unroll") for (int rt = 0; rt < 2; ++rt)                         \
        acc[s][rt] = (f32x4){0.f, 0.f, 0.f, 0.f};                              \
    _Pragma("unroll") for (int ks = 0; ks < 4; ++ks) {                         \
      bf16x8 af[2][3];                                                         \
      _Pragma("unroll") for (int rt = 0; rt < 2; ++rt)                         \
        _Pragma("unroll") for (int pl = 0; pl < 3; ++pl)                       \
          af[rt][pl] = *(const bf16x8*)&P[pl][rt * 16 + l15][ks * 32 + 8 * lq];\
      _Pragma("unroll") for (int s = 0; s < 2; ++s) {                          \
        if (s && !has1) continue;                                              \
        const unsigned short* wb = Wf +                                        \
            (size_t)((((WSEL) * 7 + (s ? ct1 : ct0)) * 4 + ks) * 3) * 512 +    \
            lane * 8;                                                          \
        const bf16x8 w0 = *(const bf16x8*)(wb);                                \
        const bf16x8 w1 = *(const bf16x8*)(wb + 512);                          \
        const bf16x8 w2 = *(const bf16x8*)(wb + 1024);                         \
        _Pragma("unroll") for (int rt = 0; rt < 2; ++rt) {                     \
          f32x4 c = acc[s][rt];                                                \
          c = __builtin_amdgcn_mfma_f32_16x16x32_bf16(af[rt][0], w0, c, 0, 0, 0); \
          c = __builtin_amdgcn_mfma_f32_16x16x32_bf16(af[rt][1], w0, c, 0, 0, 0); \
          c = __builtin_amdgcn_mfma_f32_16x16x32_bf16(af[rt][0], w1, c, 0, 0, 0); \
          c = __builtin_amdgcn_mfma_f32_16x16x32_bf16(af[rt][2], w0, c, 0, 0, 0); \
          c = __builtin_amdgcn_mfma_f32_16x16x32_bf16(af[rt][0], w2, c, 0, 0, 0); \
          c = __builtin_amdgcn_mfma_f32_16x16x32_bf16(af[rt][1], w1, c, 0, 0, 0); \
          acc[s][rt] = c;                                                      \
        }                                                                      \
      }                                                                        \
    }                                                                          \
  } while (0)

  GEMM_PHASE(0);         // phase 1: E @ W1

  // prefetch e_old for epilogue 2 (independent of LDS; GEMM2 hides latency)
  float eold[2][2][4];
#pragma unroll
  for (int s = 0; s < 2; ++s) {
    if (s && !has1) continue;
    const int col = (s ? ct1 : ct0) * 16 + l15;
#pragma unroll
    for (int rt = 0; rt < 2; ++rt)
#pragma unroll
      for (int r = 0; r < 4; ++r) {
        const int row = rt * 16 + lq * 4 + r;
        eold[s][rt][r] = (col < H) ? e[(size_t)(row0 + row) * H + col] : 0.f;
      }
  }

  __syncthreads();       // all E-plane reads complete before F overwrites

  // epilogue 1: relu(C + dots + b1) -> split -> F planes (recycle P)
#pragma unroll
  for (int s = 0; s < 2; ++s) {
    if (s && !has1) continue;
    const int col = (s ? ct1 : ct0) * 16 + l15;
    const float bias = b1sh[col];
#pragma unroll
    for (int rt = 0; rt < 2; ++rt) {
#pragma unroll
      for (int r = 0; r < 4; ++r) {
        const int row = rt * 16 + lq * 4 + r;
        float v = acc[s][rt][r] + dsh[row] + bias;
        v = fmaxf(v, 0.f);
        const unsigned short hi = bf16_rne(v);
        const float r1 = v - bf16_to_f(hi);
        const unsigned short mi = bf16_rne(r1);
        const unsigned short lo = bf16_rne(r1 - bf16_to_f(mi));
        P[0][row][col] = hi;
        P[1][row][col] = mi;
        P[2][row][col] = lo;
      }
    }
  }
  __syncthreads();       // F planes visible to all waves

  GEMM_PHASE(1);         // phase 2: F @ W2

  // epilogue 2: E += C + b2 ; store + rowsum (shfl-reduced across lq)
#pragma unroll
  for (int s = 0; s < 2; ++s) {
    if (s && !has1) continue;
    const int col = (s ? ct1 : ct0) * 16 + l15;
    const float bias = b2sh[col];
    float psum = 0.f;
#pragma unroll
    for (int rt = 0; rt < 2; ++rt) {
#pragma unroll
      for (int r = 0; r < 4; ++r) {
        const int row = rt * 16 + lq * 4 + r;
        const float en = eold[s][rt][r] + acc[s][rt][r] + bias;
        if (col < H) {
          e[(size_t)(row0 + row) * H + col] = en;
          psum += en;
        }
      }
    }
    psum += __shfl_down(psum, 32);
    psum += __shfl_down(psum, 16);
    if (lane < 16 && col < H) atomicAdd(&sacc[col], psum);
  }
  __syncthreads();
  if (tid < H) atomicAdd(&S[i * H + tid], sacc[tid]);
}

// ---------------------------------------------------------------------------
// dV = S @ W_dv1 + N*b_dv1 ;  h += dV @ W_dv2 + b_dv2
__global__ void k_node(const float* __restrict__ S, const float* __restrict__ Wdv1,
                       const float* __restrict__ bdv1, const float* __restrict__ Wdv2,
                       const float* __restrict__ bdv2, float* __restrict__ h) {
  __shared__ float Ssh[104];
  __shared__ float t1[104];
  const int i = blockIdx.x;
  const int k = threadIdx.x;
  if (k < H) Ssh[k] = S[i * H + k];
  __syncthreads();
  if (k < H) {
    float acc = 768.0f * bdv1[k];
    for (int m = 0; m < H; ++m) acc = fmaf(Ssh[m], Wdv1[m * H + k], acc);
    t1[k] = acc;
  }
  __syncthreads();
  if (k < H) {
    float acc = bdv2[k];
    for (int m = 0; m < H; ++m) acc = fmaf(t1[m], Wdv2[m * H + k], acc);
    h[i * H + k] += acc;
  }
}

// ---------------------------------------------------------------------------
extern "C" void kernel_launch(void* const* d_in, const int* in_sizes, int n_in,
                              void* d_out, int out_size, void* d_ws, size_t ws_size,
                              hipStream_t stream) {
  const float* nf   = (const float*)d_in[0];
  const float* ea   = (const float*)d_in[1];
  const float* Wn   = (const float*)d_in[2];
  const float* bn   = (const float*)d_in[3];
  const float* We   = (const float*)d_in[4];
  const float* be   = (const float*)d_in[5];
  const float* Weij = (const float*)d_in[6];
  const float* beij = (const float*)d_in[7];
  const float* Wi   = (const float*)d_in[8];
  const float* Wj   = (const float*)d_in[9];
  const float* Wde  = (const float*)d_in[10];
  const float* bde  = (const float*)d_in[11];
  const float* Wdv1 = (const float*)d_in[12];
  const float* bdv1 = (const float*)d_in[13];
  const float* Wdv2 = (const float*)d_in[14];
  const float* bdv2 = (const float*)d_in[15];

  float* h = (float*)d_out;            // (768,100) output 0
  float* e = h + NN * H;               // (768*768,100) output 1 (in-place)

  float* ws = (float*)d_ws;
  float* fi = ws;                      // NN*128 f32  (also reused for Wf)
  float* fj = fi + NN * 128;           // NN*128 f32
  float* dv = fj + NN * 128;           // NN*NN f32
  float* S  = dv + NN * NN;            // NN*H  f32
  // W fragment planes overlap the fi region: fi is dead after k_dots each
  // iter, rebuilt by k_fifj next iter. 56*3*512 u16 = 172 KB < fi's 393 KB.
  unsigned short* Wf = (unsigned short*)fi;

  k_init_h<<<(NN * H) / 256, 256, 0, stream>>>(nf, Wn, bn, h);
  k_init_e<<<(NN * NN) / 8, 256, 0, stream>>>(ea, We, be, e);
  for (int it = 0; it < ITERS; ++it) {
    k_fifj<<<NN, 256, 0, stream>>>(h, Wi, Wj, fi, fj);
    k_dots<<<dim3(NN / 16, NN / 16), dim3(16, 16), 0, stream>>>(fi, fj, dv);
    hipMemsetAsync(S, 0, NN * H * sizeof(float), stream);
    k_splitW<<<56, 64, 0, stream>>>(Weij, Wde, Wf);
    k_edge_mfma<<<(NN * NN) / BM, 256, 0, stream>>>(Wf, beij, bde, dv, e, S);
    k_node<<<NN, 128, 0, stream>>>(S, Wdv1, bdv1, Wdv2, bdv2, h);
  }
}